// Round 8
// baseline (794.353 us; speedup 1.0000x reference)
//
#include <hip/hip_runtime.h>
#include <hip/hip_bf16.h>
#include <math.h>

// B=16, N=512, D=256, L=4, H=8, HS=64, FF=1024; M = B*N = 8192.
// Precision plan (exponential activation growth => only last-layer error matters):
//  - logit path (K, Q, U, QK^T, P): hi bf16
//  - V / dT@V / proj: hi bf16 (single-layer ~0.2-0.4% rel err, budget 2%)
//  - trunk (ff1, ff2, X, mha, lm): split-bf16  A@B ~= Ah@Bh + Ah@Bl + Al@Bh
// mfma_f32_16x16x32_bf16: A row=lane&15, k=(lane>>4)*8+e; B col=lane&15 same k;
// D col=lane&15, row=(lane>>4)*4+reg.

typedef __attribute__((ext_vector_type(8))) short bf16x8;
typedef __attribute__((ext_vector_type(4))) float f32x4;
typedef unsigned long long u64;

#define NEG_INF (-__builtin_inff())

__device__ __forceinline__ short f2bf(float x) {
  unsigned u = __float_as_uint(x);
  return (short)((u + 0x7FFFu + ((u >> 16) & 1u)) >> 16);
}
__device__ __forceinline__ float bf2f(short h) {
  return __uint_as_float(((unsigned)(unsigned short)h) << 16);
}
__device__ __forceinline__ void split_bf(float x, short& hi, short& lo) {
  hi = f2bf(x); lo = f2bf(x - bf2f(hi));
}
__device__ __forceinline__ float swishf(float x) { return x / (1.0f + __expf(-x)); }
__device__ __forceinline__ f32x4 mfma16(bf16x8 a, bf16x8 b, f32x4 c) {
  return __builtin_amdgcn_mfma_f32_16x16x32_bf16(a, b, c, 0, 0, 0);
}
__device__ __forceinline__ void gload16(const void* g, void* l) {
  __builtin_amdgcn_global_load_lds(
      (const __attribute__((address_space(1))) void*)g,
      (__attribute__((address_space(3))) void*)l, 16, 0, 0);
}
__device__ __forceinline__ unsigned cvtpk(float a, float b) {  // lo=bf16(a), hi=bf16(b)
  unsigned r;
  asm("v_cvt_pk_bf16_f32 %0, %1, %2" : "=v"(r) : "v"(a), "v"(b));
  return r;
}

// ---------------- weight transpose + split (P planes) ----------------
template<int P>
__global__ __launch_bounds__(256)
void wsplit(const float* __restrict__ in, short* __restrict__ oh, short* __restrict__ ol,
            int R, int C, int zh, long outLS)
{
  __shared__ float T[64][65];
  const int z = blockIdx.z;
  const long zin = (long)z * R * C;
  const long zout = (long)(z / zh) * outLS + (long)(z % zh) * R * C;
  const int r0 = blockIdx.y << 6, c0 = blockIdx.x << 6;
  const int lc = threadIdx.x & 63, p = threadIdx.x >> 6;
#pragma unroll
  for (int q = 0; q < 16; ++q) {
    int rr = p + q * 4;
    T[rr][lc] = in[zin + (long)(r0 + rr) * C + c0 + lc];
  }
  __syncthreads();
#pragma unroll
  for (int q = 0; q < 16; ++q) {
    int cr = p + q * 4;
    float x = T[lc][cr];
    long off = zout + (long)(c0 + cr) * R + r0 + lc;
    short hi = f2bf(x);
    oh[off] = hi;
    if (P == 2) ol[off] = f2bf(x - bf2f(hi));
  }
}

// ---------------- dag -> dT bf16 (hi) + bitmasks ----------------
__global__ __launch_bounds__(512)
void prep_dt(const int* __restrict__ dag, short* __restrict__ dt0, short* __restrict__ dt1,
             u64* __restrict__ bits0, u64* __restrict__ bits1)
{
  int i = blockIdx.x, j = threadIdx.x;
  bool v0 = dag[j * 512 + i] > 0;
  bool v1 = v0 || (i == j);
  const short one = (short)0x3F80;
  dt0[i * 512 + j] = v0 ? one : (short)0;
  dt1[i * 512 + j] = v1 ? one : (short)0;
  u64 b0 = __ballot(v0), b1 = __ballot(v1);
  if ((j & 63) == 0) { bits0[i * 8 + (j >> 6)] = b0; bits1[i * 8 + (j >> 6)] = b1; }
}

__global__ __launch_bounds__(256)
void prep_x(const float* __restrict__ X, short* __restrict__ Xh, short* __restrict__ Xl)
{
  int idx = blockIdx.x * 256 + threadIdx.x;
  short hi, lo; split_bf(X[idx], hi, lo);
  Xh[idx] = hi; Xl[idx] = lo;
}

__global__ __launch_bounds__(256)
void pack_kq(const float* __restrict__ bk, const float* __restrict__ bq,
             float* __restrict__ bkq)
{
  int t = blockIdx.x * 256 + threadIdx.x;
  if (t >= 4096) return;
  int l = t >> 10, r = t & 1023;
  bkq[t] = (r < 512) ? bk[l * 512 + r] : bq[l * 512 + r - 512];
}

// ---------------- unified MFMA GEMM, 2-phase prefetch ----------------
// A (M,K) AP planes (+z*sA); BT (N,K) BP planes, stride ldb, +z*sB.
// OM 0: row-major OP planes via f32-LDS coalesced epilogue.
// OM 1: f32 direct.
// OM 2: transpose-scatter (b,h,hs,n) planes (V).
// OM 3: KQ fused: n0<512 -> K row-major hi (coalesced path); else Q^T plane *0.125 -> Ch2.
template<int BM, int BN, int AP, int BP, int OM, int OP, bool ACT, bool BIAS, bool RES>
__global__ __launch_bounds__(256)
void gemm(const short* __restrict__ Ah, const short* __restrict__ Al,
          const short* __restrict__ BTh, const short* __restrict__ BTl,
          const float* __restrict__ bias,
          const short* __restrict__ ResH, const short* __restrict__ ResL,
          float* __restrict__ Cf, short* __restrict__ Ch, short* __restrict__ Cl,
          short* __restrict__ Ch2,
          int K, int ldb, int ldc, long sA, long sB, long sC)
{
  constexpr int MR = BM / 32, NR = BN / 32;
  constexpr int ABUF = BM * 32, BBUF = BN * 32;
  constexpr int STG = AP * ABUF + BP * BBUF;
  constexpr int TSZ2 = (OM == 2 || OM == 3) ? BN * (BM + 8) : 0;
  constexpr int TSZF = (OM == 0 || OM == 3) ? BM * (BN + 4) * 2 : 0;
  constexpr int SM1 = (2 * STG > TSZ2) ? 2 * STG : TSZ2;
  constexpr int SM = (SM1 > TSZF) ? SM1 : TSZF;
  __shared__ __align__(16) short smem[SM];

  const int z = blockIdx.z;
  const short* pAh = Ah + (long)z * sA;
  const short* pAl = Al + (long)z * sA;
  const short* pBh = BTh + (long)z * sB;
  const short* pBl = BTl + (long)z * sB;
  const int n0 = blockIdx.x * BN, m0 = blockIdx.y * BM;
  const int tid = threadIdx.x, lane = tid & 63, w = tid >> 6, g = lane >> 4, c = lane & 15;
  const int wm = w >> 1, wn = w & 1;

  auto stage = [&](int bb, int k0) {
    short* LA = smem + bb * STG;
    short* LB = LA + AP * ABUF;
#pragma unroll
    for (int p = 0; p < AP; ++p) {
      const short* src = p ? pAl : pAh;
#pragma unroll
      for (int t = 0; t < BM / 64; ++t) {
        int u = t * 256 + tid, gi = u / BM, row = u % BM;
        gload16(src + (long)(m0 + row) * K + k0 + gi * 8, LA + p * ABUF + u * 8);
      }
    }
#pragma unroll
    for (int p = 0; p < BP; ++p) {
      const short* src = p ? pBl : pBh;
#pragma unroll
      for (int t = 0; t < BN / 64; ++t) {
        int u = t * 256 + tid, gi = u / BN, col = u % BN;
        gload16(src + (long)(n0 + col) * ldb + k0 + gi * 8, LB + p * BBUF + u * 8);
      }
    }
  };

  f32x4 acc[MR][NR] = {};
  stage(0, 0);
  const int nk = K >> 5;
  for (int ks = 0; ks < nk; ++ks) {
    const int cur = ks & 1;
    __syncthreads();
    if (ks + 1 < nk) stage(cur ^ 1, (ks + 1) << 5);

    short* LA = smem + cur * STG;
    short* LB = LA + AP * ABUF;
    bf16x8 a_h[MR], a_l[MR], b_h[NR], b_l[NR];
#pragma unroll
    for (int i = 0; i < MR; ++i) {
      int idx = (g * BM + wm * (BM / 2) + i * 16 + c) * 8;
      a_h[i] = *(const bf16x8*)(LA + idx);
      if (AP == 2) a_l[i] = *(const bf16x8*)(LA + ABUF + idx);
    }
#pragma unroll
    for (int j = 0; j < NR; ++j) {
      int idx = (g * BN + wn * (BN / 2) + j * 16 + c) * 8;
      b_h[j] = *(const bf16x8*)(LB + idx);
      if (BP == 2) b_l[j] = *(const bf16x8*)(LB + BBUF + idx);
    }
    __builtin_amdgcn_s_setprio(1);
#pragma unroll
    for (int i = 0; i < MR; ++i)
#pragma unroll
      for (int j = 0; j < NR; ++j) {
        acc[i][j] = mfma16(a_h[i], b_h[j], acc[i][j]);
        if (BP == 2) acc[i][j] = mfma16(a_h[i], b_l[j], acc[i][j]);
        if (AP == 2) acc[i][j] = mfma16(a_l[i], b_h[j], acc[i][j]);
      }
    __builtin_amdgcn_s_setprio(0);
  }

  if constexpr (OM == 1) {
    // direct f32 stores (col = c across lanes -> 64B runs)
#pragma unroll
    for (int j = 0; j < NR; ++j) {
      int cl = wn * (BN / 2) + j * 16 + c;
      float bv = BIAS ? bias[n0 + cl] : 0.f;
#pragma unroll
      for (int i = 0; i < MR; ++i)
#pragma unroll
        for (int rr = 0; rr < 4; ++rr) {
          long row = m0 + wm * (BM / 2) + i * 16 + g * 4 + rr;
          float x = acc[i][j][rr] + bv;
          if (ACT) x = swishf(x);
          Cf[(long)z * sC + row * ldc + n0 + cl] = x;
        }
    }
    return;
  }

  if constexpr (OM == 0 || OM == 3) {
    if (OM == 0 || n0 < 512) {
      // coalesced row-major epilogue via f32 LDS transpose
      __syncthreads();
      float* Tf = (float*)smem;
      constexpr int LDT = BN + 4;
#pragma unroll
      for (int j = 0; j < NR; ++j) {
        int cl = wn * (BN / 2) + j * 16 + c;
        float bv = BIAS ? bias[n0 + cl] : 0.f;
#pragma unroll
        for (int i = 0; i < MR; ++i)
#pragma unroll
          for (int rr = 0; rr < 4; ++rr) {
            int rowl = wm * (BM / 2) + i * 16 + g * 4 + rr;
            float x = acc[i][j][rr] + bv;
            if (ACT) x = swishf(x);
            Tf[rowl * LDT + cl] = x;
          }
      }
      __syncthreads();
      constexpr int CH = BN / 8, NT = BM * CH / 256;
#pragma unroll
      for (int t = 0; t < NT; ++t) {
        int idx = t * 256 + tid, row = idx / CH, ch = idx % CH;
        long base = (long)z * sC + (long)(m0 + row) * ldc + (OM == 3 ? (n0 & 511) : n0) + ch * 8;
        float x8[8];
#pragma unroll
        for (int e = 0; e < 8; ++e) x8[e] = Tf[row * LDT + ch * 8 + e];
        if (RES) {
          bf16x8 rh = *(const bf16x8*)(ResH + base);
          bf16x8 rl8 = *(const bf16x8*)(ResL + base);
#pragma unroll
          for (int e = 0; e < 8; ++e) x8[e] += bf2f(rh[e]) + bf2f(rl8[e]);
        }
        short h8[8], l8[8];
#pragma unroll
        for (int e = 0; e < 8; ++e) split_bf(x8[e], h8[e], l8[e]);
        *(bf16x8*)(Ch + base) = *(const bf16x8*)&h8[0];
        if (OP == 2) *(bf16x8*)(Cl + base) = *(const bf16x8*)&l8[0];
      }
      return;
    }
  }

  if constexpr (OM == 2 || OM == 3) {
    // transpose-scatter -> (b,h,hs,n) planes
    short (*T)[BM + 8] = reinterpret_cast<short(*)[BM + 8]>(smem);
    const int h0 = (n0 & 511) >> 6;
    const int b = m0 >> 9, nn0 = m0 & 511;
    constexpr int NP = (OM == 3) ? 1 : OP;
#pragma unroll
    for (int p = 0; p < NP; ++p) {
      __syncthreads();
#pragma unroll
      for (int j = 0; j < NR; ++j) {
        int cl = wn * (BN / 2) + j * 16 + c;
        float bv = BIAS ? bias[n0 + cl] : 0.f;
#pragma unroll
        for (int i = 0; i < MR; ++i)
#pragma unroll
          for (int rr = 0; rr < 4; ++rr) {
            int rowl = wm * (BM / 2) + i * 16 + g * 4 + rr;
            float x = acc[i][j][rr] + bv;
            if (ACT) x = swishf(x);
            if (OM == 3) x *= 0.125f;          // fold 1/sqrt(hs) into Q
            short hi = f2bf(x);
            T[cl][rowl] = p ? f2bf(x - bf2f(hi)) : hi;
          }
      }
      __syncthreads();
      short* dp = (OM == 3) ? Ch2 : (p ? Cl : Ch);
      constexpr int RC = BM / 8;
#pragma unroll
      for (int q = 0; q < BN * BM / 2048; ++q) {
        int idx = q * 256 + tid, cl = idx / RC, r8 = (idx % RC) * 8;
        long ob = ((long)(b * 8 + h0 + (cl >> 6)) << 15) + (long)(cl & 63) * 512 + nn0 + r8;
        *(bf16x8*)(dp + ob) = *(const bf16x8*)&T[cl][r8];
      }
    }
  }
}

// ---------------- swapped-operand masked flash attention ----------------
// S^T = K @ U^T (per-lane P rows), per-lane online softmax, O^T = V^T @ P^T.
// O = (exp(s-m)/l)@V + OI;  OIT is dT@V transposed (hs,n), f32.
// grid: x = bh (XCD locality on K/V), y = i-tile.
__global__ __launch_bounds__(256)
void attn4(const short* __restrict__ Uh, const short* __restrict__ Kh,
           const short* __restrict__ VTh, const u64* __restrict__ bits,
           const float* __restrict__ OIT, short* __restrict__ Oh)
{
  __shared__ __align__(16) short LK[2][4096];   // K tile [d-grp][j][8]
  __shared__ __align__(16) short LV[2][4096];   // V^T tile [j-grp][hs][8]

  const int bh = blockIdx.x, b = bh >> 3, hd = bh & 7;
  const int i0 = blockIdx.y << 6;
  const int tid = threadIdx.x, lane = tid & 63, w = tid >> 6, g = lane >> 4, c = lane & 15;
  const int istrip = i0 + w * 16;
  const long plane = (long)bh << 15;

  auto stage = [&](int bb, int jt) {
#pragma unroll
    for (int t = 0; t < 2; ++t) {
      int u = t * 256 + tid, gi = u >> 6, j = u & 63;
      long ko = (long)(b * 512 + jt * 64 + j) * 512 + hd * 64 + gi * 8;
      gload16(Kh + ko, &LK[bb][0] + u * 8);
      long vo = plane + (long)j * 512 + jt * 64 + gi * 8;   // j slot = hs row
      gload16(VTh + vo, &LV[bb][0] + u * 8);
    }
  };

  stage(0, 0);

  bf16x8 uf[2];   // B-operand: U[i=istrip+c][d]  (U pre-scaled by 1/8)
#pragma unroll
  for (int ks = 0; ks < 2; ++ks)
    uf[ks] = *(const bf16x8*)(Uh + plane + (long)(istrip + c) * 64 + ks * 32 + g * 8);

  float m_run = NEG_INF, l_run = 0.f;
  f32x4 oeT[4] = {};
  const int srcA = (g & 1) * 32 + c, srcB = srcA + 16;
  const bool ghi = (g >> 1) != 0;

  for (int jt = 0; jt < 8; ++jt) {
    const int cur = jt & 1;
    __syncthreads();
    if (jt + 1 < 8) stage(cur ^ 1, jt + 1);

    // S^T[j][i]: lane (g,c) holds j = jt*64 + ct*16 + g*4 + rr for i = istrip+c
    f32x4 sacc[4] = {};
    __builtin_amdgcn_s_setprio(1);
#pragma unroll
    for (int ct = 0; ct < 4; ++ct)
#pragma unroll
      for (int ks = 0; ks < 2; ++ks) {
        bf16x8 kf = *(const bf16x8*)&LK[cur][((ks * 4 + g) * 64 + ct * 16 + c) * 8];
        sacc[ct] = mfma16(kf, uf[ks], sacc[ct]);
      }
    __builtin_amdgcn_s_setprio(0);

    const u64 wb = bits[(long)(istrip + c) * 8 + jt];

    // per-lane masked max (in-lane) + 2-step cross-g combine
    float vmax = NEG_INF;
#pragma unroll
    for (int ct = 0; ct < 4; ++ct)
#pragma unroll
      for (int rr = 0; rr < 4; ++rr)
        if ((wb >> (ct * 16 + g * 4 + rr)) & 1ull) vmax = fmaxf(vmax, sacc[ct][rr]);
    vmax = fmaxf(vmax, __shfl_xor(vmax, 16, 64));
    vmax = fmaxf(vmax, __shfl_xor(vmax, 32, 64));
    float mnew = fmaxf(m_run, vmax);
    float sf = (m_run > NEG_INF) ? __expf(m_run - mnew) : 0.f;

    float p[4][4], ps = 0.f;
#pragma unroll
    for (int ct = 0; ct < 4; ++ct)
#pragma unroll
      for (int rr = 0; rr < 4; ++rr) {
        bool bs = (wb >> (ct * 16 + g * 4 + rr)) & 1ull;
        float pe = bs ? __expf(sacc[ct][rr] - mnew) : 0.f;
        p[ct][rr] = pe; ps += pe;
      }
    ps += __shfl_xor(ps, 16, 64);
    ps += __shfl_xor(ps, 32, 64);
    l_run = l_run * sf + ps;
    m_run = mnew;
#pragma unroll
    for (int ht = 0; ht < 4; ++ht)
#pragma unroll
      for (int rr = 0; rr < 4; ++rr) oeT[ht][rr] *= sf;

    // pack P to bf16 pairs and redistribute into PV B-fragments
    unsigned q0[4], q1[4];
#pragma unroll
    for (int ct = 0; ct < 4; ++ct) {
      q0[ct] = cvtpk(p[ct][0], p[ct][1]);
      q1[ct] = cvtpk(p[ct][2], p[ct][3]);
    }
#pragma unroll
    for (int ksp = 0; ksp < 2; ++ksp) {
      unsigned a00 = __shfl(q0[2 * ksp], srcA, 64), a01 = __shfl(q0[2 * ksp + 1], srcA, 64);
      unsigned a10 = __shfl(q1[2 * ksp], srcA, 64), a11 = __shfl(q1[2 * ksp + 1], srcA, 64);
      unsigned b00 = __shfl(q0[2 * ksp], srcB, 64), b01 = __shfl(q0[2 * ksp + 1], srcB, 64);
      unsigned b10 = __shfl(q1[2 * ksp], srcB, 64), b11 = __shfl(q1[2 * ksp + 1], srcB, 64);
      union { unsigned u[4]; bf16x8 v; } pa;
      pa.u[0] = ghi ? a01 : a00;
      pa.u[1] = ghi ? a11 : a10;
      pa.u[2] = ghi ? b01 : b00;
      pa.u[3] = ghi ? b11 : b10;
      __builtin_amdgcn_s_setprio(1);
#pragma unroll
      for (int ht = 0; ht < 4; ++ht) {
        bf16x8 vf = *(const bf16x8*)&LV[cur][((ksp * 4 + g) * 64 + ht * 16 + c) * 8];
        oeT[ht] = mfma16(vf, pa.v, oeT[ht]);
      }
      __builtin_amdgcn_s_setprio(0);
    }
  }

  const float rl = (l_run > 0.f) ? 1.f / l_run : 0.f;

  // normalize, add OI^T, transpose via LDS, coalesced store
  __syncthreads();
  short* T = (short*)&LK[0][0];   // [64 i][72] bf16
#pragma unroll
  for (int ht = 0; ht < 4; ++ht)
#pragma unroll
    for (int rr = 0; rr < 4; ++rr) {
      int hs = ht * 16 + g * 4 + rr;
      float x = oeT[ht][rr] * rl + OIT[plane + (long)hs * 512 + i0 + w * 16 + c];
      T[(w * 16 + c) * 72 + hs] = f2bf(x);
    }
  __syncthreads();
#pragma unroll
  for (int t = 0; t < 2; ++t) {
    int idx = t * 256 + tid, row = idx >> 3, ch = idx & 7;
    *(bf16x8*)(Oh + (long)(b * 512 + i0 + row) * 512 + hd * 64 + ch * 8) =
        *(const bf16x8*)&T[row * 72 + ch * 8];
  }
}

// ---------------- host ----------------
extern "C" void kernel_launch(void* const* d_in, const int* in_sizes, int n_in,
                              void* d_out, int out_size, void* d_ws, size_t ws_size,
                              hipStream_t stream)
{
  const float* X   = (const float*)d_in[0];
  const int*   dag = (const int*)d_in[1];
  const float* Wk  = (const float*)d_in[2];
  const float* bk  = (const float*)d_in[3];
  const float* Wq  = (const float*)d_in[4];
  const float* bq  = (const float*)d_in[5];
  const float* Wv  = (const float*)d_in[6];
  const float* bv  = (const float*)d_in[7];
  const float* Wp  = (const float*)d_in[8];
  const float* bp  = (const float*)d_in[9];
  const float* W1  = (const float*)d_in[10];
  const float* b1  = (const float*)d_in[11];
  const float* W2  = (const float*)d_in[12];
  const float* b2  = (const float*)d_in[13];
  const float* Wlm = (const float*)d_in[14];
  const float* blm = (const float*)d_in[15];
  float* out = (float*)d_out;

  // ---- workspace (~73 MB) ----
  char* p = (char*)d_ws;
  auto alloc = [&](size_t n) { void* r = p; p += (n + 255) & ~(size_t)255; return r; };
  short* WkqTh = (short*)alloc(1048576 * 2);   // [l][1024][256] hi (K|Q)
  short* WvTh = (short*)alloc(524288 * 2);
  short* WpTh = (short*)alloc(524288 * 2);
  short* W1Th = (short*)alloc(1048576 * 2); short* W1Tl = (short*)alloc(1048576 * 2);
  short* W2Th = (short*)alloc(1048576 * 2); short* W2Tl = (short*)alloc(1048576 * 2);
  short* WlmTh = (short*)alloc(65536 * 2); short* WlmTl = (short*)alloc(65536 * 2);
  float* bkq = (float*)alloc(4096 * 4);
  short* dt0b = (short*)alloc(262144 * 2); short* dt1b = (short*)alloc(262144 * 2);
  u64* bits0 = (u64*)alloc(4096 * 8); u64* bits1 = (u64*)alloc(4096 * 8);
  short* Xh = (short*)alloc(2097152 * 2); short* Xl = (short*)alloc(2097152 * 2);
  short* Kh  = (short*)alloc(4194304 * 2);   // also mha hi+lo (2M+2M)
  short* QTh = (short*)alloc(4194304 * 2);   // Q^T; then O hi; ff1H spans QTh+VTh
  short* VTh = (short*)alloc(4194304 * 2);
  short* Uh  = (short*)alloc(4194304 * 2);   // U; ff1L spans Uh + OIT/2
  float* OIT = (float*)alloc(4194304 * 4);
  short* mhaH = Kh, *mhaL = Kh + 2097152;
  short* Oh = QTh;
  short* ff1H = QTh;   // 8192x1024 hi spans QTh..VTh
  short* ff1L = Uh;    // lo spans Uh..first half of OIT

  // ---- prep ----
  wsplit<1><<<dim3(1, 4, 32), 256, 0, stream>>>(Wk, WkqTh, nullptr, 256, 64, 8, 262144);
  wsplit<1><<<dim3(1, 4, 32), 256, 0, stream>>>(Wq, WkqTh + 131072, nullptr, 256, 64, 8, 262144);
  wsplit<1><<<dim3(1, 4, 32), 256, 0, stream>>>(Wv, WvTh, nullptr, 256, 64, 8, 131072);
  wsplit<1><<<dim3(4, 8, 4), 256, 0, stream>>>(Wp, WpTh, nullptr, 512, 256, 1, 131072);
  wsplit<2><<<dim3(16, 4, 4), 256, 0, stream>>>(W1, W1Th, W1Tl, 256, 1024, 1, 262144);
  wsplit<2><<<dim3(4, 16, 4), 256, 0, stream>>>(W2, W2Th, W2Tl, 1024, 256, 1, 262144);
  wsplit<2><<<dim3(4, 4, 1), 256, 0, stream>>>(Wlm, WlmTh, WlmTl, 256, 256, 1, 65536);
  prep_dt<<<512, 512, 0, stream>>>(dag, dt0b, dt1b, bits0, bits1);
  prep_x<<<8192, 256, 0, stream>>>(X, Xh, Xl);
  pack_kq<<<16, 256, 0, stream>>>(bk, bq, bkq);

  for (int l = 0; l < 4; ++l) {
    const short* dtb = l ? dt1b : dt0b;
    const u64* bts = l ? bits1 : bits0;
    // 1. KQ fused: K row-major hi; Q^T plane hi (x0.125)
    gemm<128, 64, 1, 1, 3, 1, true, true, false><<<dim3(16, 64), 256, 0, stream>>>(
        Xh, nullptr, WkqTh + l * 262144, nullptr, bkq + l * 1024, nullptr, nullptr,
        nullptr, Kh, nullptr, QTh, 256, 256, 512, 0, 0, 0);
    // 2. V -> V^T plane hi
    gemm<128, 64, 1, 1, 2, 1, true, true, false><<<dim3(8, 64), 256, 0, stream>>>(
        Xh, nullptr, WvTh + l * 131072, nullptr, bv + l * 512, nullptr, nullptr,
        nullptr, VTh, nullptr, nullptr, 256, 256, 0, 0, 0, 0);
    // 3. U = dT@Q (hi), batched over bh
    gemm<128, 64, 1, 1, 0, 1, false, false, false><<<dim3(1, 4, 128), 256, 0, stream>>>(
        dtb, nullptr, QTh, nullptr, nullptr, nullptr, nullptr,
        nullptr, Uh, nullptr, nullptr, 512, 512, 64, 0, 32768, 32768);
    // 4. OI^T = V^T @ dT^T (hi), f32 (bh, hs, n)
    gemm<64, 64, 1, 1, 1, 1, false, false, false><<<dim3(8, 1, 128), 256, 0, stream>>>(
        VTh, nullptr, dtb, nullptr, nullptr, nullptr, nullptr,
        OIT, nullptr, nullptr, nullptr, 512, 512, 512, 32768, 0, 32768);
    // 5. attention
    attn4<<<dim3(128, 8), 256, 0, stream>>>(Uh, Kh, VTh, bts, OIT, Oh);
    // 6. mha = swish(O@Wp+bp), hi/lo
    gemm<128, 64, 1, 1, 0, 2, true, true, false><<<dim3(4, 64), 256, 0, stream>>>(
        Oh, nullptr, WpTh + l * 131072, nullptr, bp + l * 256, nullptr, nullptr,
        nullptr, mhaH, mhaL, nullptr, 512, 512, 256, 0, 0, 0);
    // 7. ff1 = swish(mha@W1+b1), split
    gemm<128, 64, 2, 2, 0, 2, true, true, false><<<dim3(16, 64), 256, 0, stream>>>(
        mhaH, mhaL, W1Th + l * 262144, W1Tl + l * 262144, b1 + l * 1024, nullptr, nullptr,
        nullptr, ff1H, ff1L, nullptr, 256, 256, 1024, 0, 0, 0);
    // 8. X = mha + ff1@W2 + b2, split
    gemm<64, 64, 2, 2, 0, 2, false, true, true><<<dim3(4, 128), 256, 0, stream>>>(
        ff1H, ff1L, W2Th + l * 262144, W2Tl + l * 262144, b2 + l * 256, mhaH, mhaL,
        nullptr, Xh, Xl, nullptr, 1024, 1024, 256, 0, 0, 0);
  }
  // lm_head: out = X@Wlm + blm (f32)
  gemm<64, 64, 2, 2, 1, 1, false, true, false><<<dim3(4, 128), 256, 0, stream>>>(
      Xh, Xl, WlmTh, WlmTl, blm, nullptr, nullptr,
      out, nullptr, nullptr, nullptr, 256, 256, 256, 0, 0, 0);
}